// Round 14
// baseline (620.990 us; speedup 1.0000x reference)
//
#include <hip/hip_runtime.h>
#include <math.h>

#define D 128
#define T 2048
#define BATCH 4
#define HMID 512
#define NLAYER 12

#define KSPLIT 4
#define KPB (T / KSPLIT)   // 512 keys per attn block

#if defined(__has_builtin)
#if __has_builtin(__builtin_amdgcn_global_load_lds)
#define USE_GLL 1
#endif
#endif
#ifndef USE_GLL
#define USE_GLL 0
#endif

typedef unsigned short u16;
typedef __attribute__((ext_vector_type(8))) short bf16x8;
typedef __attribute__((ext_vector_type(16))) float f32x16;

__device__ inline u16 f2bf(float x) {
    unsigned u = __builtin_bit_cast(unsigned, x);
    return (u16)((u + 0x7FFFu + ((u >> 16) & 1u)) >> 16);
}
__device__ inline float bf2f(u16 v) {
    return __builtin_bit_cast(float, (unsigned)v << 16);
}
__device__ inline unsigned pkt(float a, float b) {
    return (__builtin_bit_cast(unsigned, a) >> 16) |
           (__builtin_bit_cast(unsigned, b) & 0xFFFF0000u);
}
// tanh-form gelu via exp2 (deviation <0.02 abs; mid is bf16 anyway)
__device__ inline float gelu_f(float v) {
    float y = 0.7978845608028654f * v * fmaf(0.044715f, v * v, 1.f);
    float e = exp2f(2.885390081777927f * y);
    return v * (1.f - 1.f / (e + 1.f));
}

// ================= helpers (32-row blocks, Ct pitch 132) =================
__device__ inline void build_as_fused(const float (*Ct)[132],
                                      const float* __restrict__ g,
                                      const float* __restrict__ bb,
                                      u16* As, int tid) {
    const int row = tid >> 3, e8 = tid & 7;
    float s = 0.f;
#pragma unroll
    for (int c = 0; c < 16; c++) s += Ct[row][e8 * 16 + c];
    s += __shfl_xor(s, 1); s += __shfl_xor(s, 2); s += __shfl_xor(s, 4);
    float mu = s * (1.f / D);
    float s2 = 0.f;
#pragma unroll
    for (int c = 0; c < 16; c++) {
        float d0 = Ct[row][e8 * 16 + c] - mu;
        s2 += d0 * d0;
    }
    s2 += __shfl_xor(s2, 1); s2 += __shfl_xor(s2, 2); s2 += __shfl_xor(s2, 4);
    float rs = rsqrtf(s2 * (1.f / D) + 1e-5f);
#pragma unroll
    for (int cc = 0; cc < 2; cc++) {
        int c = e8 * 2 + cc;
        u16 tmp[8];
#pragma unroll
        for (int j = 0; j < 8; j++) {
            int d = c * 8 + j;
            tmp[j] = f2bf((Ct[row][d] - mu) * rs * g[d] + bb[d]);
        }
        *(uint4*)&As[((size_t)c * 32 + (row ^ (c & 7))) * 8] = *(uint4*)tmp;
    }
}

// stage 128x128 bf16 tile; slot s holds W[row=s>>4][ch=(s&15)^(row&7)]
__device__ inline void stage_w_async(const u16* __restrict__ W, int ldw, u16* Wst, int tid) {
    const int w = tid >> 6, l = tid & 63;
#if USE_GLL
#pragma unroll
    for (int i = 0; i < 8; i++) {
        int s = i * 256 + w * 64 + l;
        int row = s >> 4, ch = (s & 15) ^ (row & 7);
        __builtin_amdgcn_global_load_lds(
            (const __attribute__((address_space(1))) void*)(W + (size_t)row * ldw + ch * 8),
            (__attribute__((address_space(3))) void*)&Wst[(i * 256 + w * 64) * 8], 16, 0, 0);
    }
#else
#pragma unroll
    for (int i = 0; i < 8; i++) {
        int s = tid + i * 256;
        int row = s >> 4, ch = (s & 15) ^ (row & 7);
        *(uint4*)&Wst[(size_t)s * 8] = *(const uint4*)(W + (size_t)row * ldw + ch * 8);
    }
#endif
}

// C[32 rows(reg)][128 n] = As(32xK128) @ Wst^T ; Wst in slot layout above
__device__ inline f32x16 mm_32x128(const u16* As, const u16* Wst, int wv, int ql, int h) {
    const int n = wv * 32 + ql, nsw = n & 7;
    f32x16 a;
#pragma unroll
    for (int r = 0; r < 16; r++) a[r] = 0.f;
#pragma unroll
    for (int s = 0; s < 8; s++) {
        int ch = 2 * s + h;
        bf16x8 af = *(const bf16x8*)&As[((size_t)ch * 32 + (ql ^ (ch & 7))) * 8];
        bf16x8 bf = *(const bf16x8*)&Wst[((size_t)n * 16 + (ch ^ nsw)) * 8];
        a = __builtin_amdgcn_mfma_f32_32x32x16_bf16(af, bf, a, 0, 0, 0);
    }
    return a;
}

// ================= weight conversion =================
__global__ __launch_bounds__(256) void conv_all(const float* __restrict__ Wq,
                                                const float* __restrict__ Wk,
                                                const float* __restrict__ Wv,
                                                const float* __restrict__ W1,
                                                const float* __restrict__ W2,
                                                u16* __restrict__ Wqkv,
                                                u16* __restrict__ W1b,
                                                u16* __restrict__ W2b, float qscale) {
    const int NQ = NLAYER * 3 * D * D;
    const int NW = NLAYER * HMID * D;
    int idx = blockIdx.x * 256 + threadIdx.x;
    if (idx < NQ) {
        int lN = idx / (3 * D * D);
        int rem = idx - lN * (3 * D * D);
        int s = rem >> 14;
        int off = rem & 16383;
        const float* src = (s == 0) ? Wq : ((s == 1) ? Wk : Wv);
        Wqkv[idx] = f2bf(src[lN * 16384 + off] * ((s == 0) ? qscale : 1.f));
    } else if (idx < NQ + NW) {
        W1b[idx - NQ] = f2bf(W1[idx - NQ]);
    } else if (idx < NQ + 2 * NW) {
        W2b[idx - NQ - NW] = f2bf(W2[idx - NQ - NW]);
    }
}

// ================= embed + LN1 + QKV (layer 0 prologue) =================
__global__ __launch_bounds__(256, 2) void embed_qkv(const int* __restrict__ x,
                                                    const float* __restrict__ pos,
                                                    const float* __restrict__ g1,
                                                    const float* __restrict__ b1g,
                                                    const u16* __restrict__ Wqkv0,
                                                    u16* __restrict__ qb, u16* __restrict__ kb,
                                                    u16* __restrict__ vt,
                                                    float* __restrict__ H) {
    __shared__ float Ct[32][132];
    __shared__ u16 As[16 * 32 * 8];
    __shared__ u16 Wst[16 * 128 * 8];
    const int tid = threadIdx.x;
    const int m0 = blockIdx.x * 32;
    const int wv = tid >> 6, l = tid & 63, h = l >> 5, ql = l & 31;
    {
        const int d = tid & 127, rr = tid >> 7;
#pragma unroll
        for (int i = 0; i < 16; i++) {
            int row = rr * 16 + i;
            int tok = m0 + row;
            int t = tok & (T - 1);
            float e = 0.f;
            if (d < 64) {
                float diff = (float)d - (float)x[tok];
                e = -0.5f * diff * diff;
            }
            float v = e + pos[(size_t)t * D + d];
            Ct[row][d] = v;
            H[(size_t)tok * D + d] = v;
        }
    }
    __syncthreads();
    build_as_fused(Ct, g1, b1g, As, tid);
#pragma unroll
    for (int sl = 0; sl < 3; sl++) {
        __syncthreads();
        stage_w_async(Wqkv0 + (size_t)sl * 128 * D, D, Wst, tid);
        __syncthreads();
        f32x16 a = mm_32x128(As, Wst, wv, ql, h);
        const int n = wv * 32 + ql;
        if (sl == 2) {
            u16* dst = vt + (size_t)(m0 >> 11) * D * T + (size_t)n * T + (m0 & (T - 1));
#pragma unroll
            for (int g = 0; g < 4; g++) {
                ushort4 o;
                o.x = f2bf(a[4 * g + 0]); o.y = f2bf(a[4 * g + 1]);
                o.z = f2bf(a[4 * g + 2]); o.w = f2bf(a[4 * g + 3]);
                *(ushort4*)(dst + 8 * g + 4 * h) = o;
            }
        } else {
            u16* dst = (sl == 0) ? qb : kb;
#pragma unroll
            for (int r = 0; r < 16; r++) {
                int row = (r & 3) + 8 * (r >> 2) + 4 * h;
                dst[(size_t)(m0 + row) * D + n] = f2bf(a[r]);
            }
        }
    }
}

// ========== MFMA flash attention: double-buffered 128-key tiles, pipelined ==========
// grid (64 qblk, KSPLIT=4). BQ=128, KPB=512 (4 tiles). LDS 128 KB, 1 block/CU,
// stage k+1 issued before computing tile k (drain at barrier ~free, R13 pattern).
__device__ inline void stage_kv(const u16* __restrict__ kgb, const u16* __restrict__ vtb,
                                int kbase, u16* Ks, u16* Vt, int tid) {
    const int w = tid >> 6, l = tid & 63;
#if USE_GLL
#pragma unroll
    for (int i = 0; i < 8; i++) {
        int s = i * 256 + w * 64 + l;
        int row = s >> 4, ch = (s & 15) ^ (row & 7);
        __builtin_amdgcn_global_load_lds(
            (const __attribute__((address_space(1))) void*)(kgb + (size_t)(kbase + row) * D + ch * 8),
            (__attribute__((address_space(3))) void*)&Ks[(i * 256 + w * 64) * 8], 16, 0, 0);
    }
#pragma unroll
    for (int i = 0; i < 8; i++) {
        int s = i * 256 + w * 64 + l;
        int dd = s >> 4, ch = (s & 15) ^ (dd & 7);
        __builtin_amdgcn_global_load_lds(
            (const __attribute__((address_space(1))) void*)(vtb + (size_t)dd * T + kbase + ch * 8),
            (__attribute__((address_space(3))) void*)&Vt[(i * 256 + w * 64) * 8], 16, 0, 0);
    }
#else
#pragma unroll
    for (int i = 0; i < 8; i++) {
        int s = tid + i * 256;
        int row = s >> 4, ch = (s & 15) ^ (row & 7);
        *(uint4*)&Ks[(size_t)s * 8] = *(const uint4*)(kgb + (size_t)(kbase + row) * D + ch * 8);
        *(uint4*)&Vt[(size_t)s * 8] = *(const uint4*)(vtb + (size_t)row * T + kbase + ch * 8);
    }
#endif
}

__global__ __launch_bounds__(256, 1) void attn_mfma(const u16* __restrict__ qg,
                                                    const u16* __restrict__ kg,
                                                    const u16* __restrict__ vtg,
                                                    u16* __restrict__ Op,
                                                    float* __restrict__ ml) {
    __shared__ u16 KsBuf[2][128 * 128];   // 2 x 32 KB
    __shared__ u16 VtBuf[2][128 * 128];   // 2 x 32 KB
    const int tid = threadIdx.x;
    const int w = tid >> 6;
    const int l = tid & 63;
    const int h = l >> 5;
    const int ql = l & 31;
    const int qblk = blockIdx.x;
    const int ks = blockIdx.y;
    const int b = qblk >> 4;

    const size_t qrow = (size_t)qblk * 128 + w * 32 + ql;
    bf16x8 qf[8];
#pragma unroll
    for (int c = 0; c < 8; c++)
        qf[c] = *(const bf16x8*)(qg + qrow * D + c * 16 + h * 8);

    f32x16 ot[4];
#pragma unroll
    for (int t = 0; t < 4; t++)
#pragma unroll
        for (int r = 0; r < 16; r++) ot[t][r] = 0.f;
    float l_run = 0.f;

    const u16* kgb = kg + (size_t)b * T * D;
    const u16* vtb = vtg + (size_t)b * D * T;
    const int qsw = ql & 7;

    stage_kv(kgb, vtb, ks * KPB, KsBuf[0], VtBuf[0], tid);
    __syncthreads();

    for (int kt = 0; kt < KPB / 128; kt++) {
        const int p = kt & 1;
        if (kt + 1 < KPB / 128)
            stage_kv(kgb, vtb, ks * KPB + (kt + 1) * 128, KsBuf[1 - p], VtBuf[1 - p], tid);
        const u16* Ks = KsBuf[p];
        const u16* Vt = VtBuf[p];
        uint2 pk[4][4];
        float rs = 0.f;
#pragma unroll
        for (int s4 = 0; s4 < 4; s4++) {
            const int krow = s4 * 32 + ql;
            f32x16 st;
#pragma unroll
            for (int r = 0; r < 16; r++) st[r] = 0.f;
#pragma unroll
            for (int c = 0; c < 8; c++) {
                bf16x8 kf = *(const bf16x8*)&Ks[((size_t)krow * 16 + ((2 * c + h) ^ qsw)) * 8];
                st = __builtin_amdgcn_mfma_f32_32x32x16_bf16(kf, qf[c], st, 0, 0, 0);
            }
#pragma unroll
            for (int r = 0; r < 16; r++) {
                float p2 = exp2f(st[r]);
                st[r] = p2;
                rs += p2;
            }
#pragma unroll
            for (int g = 0; g < 4; g++) {
                pk[s4][g].x = pkt(st[4 * g + 0], st[4 * g + 1]);
                pk[s4][g].y = pkt(st[4 * g + 2], st[4 * g + 3]);
            }
        }
        rs += __shfl_xor(rs, 32);
        l_run += rs;
#pragma unroll
        for (int c = 0; c < 8; c++) {
            const int s4 = c >> 1, cc = c & 1;
            uint2 own = h ? pk[s4][2 * cc + 1] : pk[s4][2 * cc];
            uint2 snd = h ? pk[s4][2 * cc] : pk[s4][2 * cc + 1];
            uint2 rcv;
            rcv.x = (unsigned)__shfl_xor((int)snd.x, 32);
            rcv.y = (unsigned)__shfl_xor((int)snd.y, 32);
            uint4 fr;
            fr.x = h ? rcv.x : own.x;
            fr.y = h ? rcv.y : own.y;
            fr.z = h ? own.x : rcv.x;
            fr.w = h ? own.y : rcv.y;
            bf16x8 pf = __builtin_bit_cast(bf16x8, fr);
            const int kch = 2 * c + h;
#pragma unroll
            for (int t = 0; t < 4; t++) {
                bf16x8 vf = *(const bf16x8*)&Vt[((size_t)(t * 32 + ql) * 16 + (kch ^ qsw)) * 8];
                ot[t] = __builtin_amdgcn_mfma_f32_32x32x16_bf16(vf, pf, ot[t], 0, 0, 0);
            }
        }
        __syncthreads();   // drains prefetch kt+1 — issued ~2000 cyc ago, ~free
    }
    size_t base = (((size_t)(qblk * KSPLIT + ks)) * 4 + w) * (128 * 32);
#pragma unroll
    for (int t = 0; t < 4; t++)
#pragma unroll
        for (int r = 0; r < 16; r++) {
            int dd = (r & 3) + 8 * (r >> 2) + 4 * h + 32 * t;
            Op[base + (size_t)dd * 32 + ql] = f2bf(ot[t][r]);
        }
    if (h == 0) {
        int qi = w * 32 + ql;
        ml[(size_t)(qblk * KSPLIT + ks) * 256 + 128 + qi] = l_run;
    }
}

// ====== layer tail: merge + resid + LN2 + MLP + resid + LN1' + QKV' ======
// Double-buffered pipelined weight staging (R13 pattern), LDS ~97 KB, 1 block/CU.
template <int LAST>
__global__ __launch_bounds__(256, 1) void layer_tail(
    const u16* __restrict__ Op, const float* __restrict__ ml,
    float* __restrict__ H,
    const float* __restrict__ g2, const float* __restrict__ b2l,
    const u16* __restrict__ W1l, const float* __restrict__ b1l,
    const u16* __restrict__ W2l, const float* __restrict__ b2bias,
    const float* __restrict__ g1n, const float* __restrict__ b1n,
    const u16* __restrict__ Wqkvn,
    u16* __restrict__ qb, u16* __restrict__ kb, u16* __restrict__ vt,
    const float* __restrict__ Wro, const float* __restrict__ bro,
    float* __restrict__ outp) {
    __shared__ float Ct[32][132];
    __shared__ float Linv[32];
    __shared__ u16 As[16 * 32 * 8];
    __shared__ u16 midS[16 * 32 * 8];
    __shared__ u16 WstBuf[2][16 * 128 * 8];

    const int tid = threadIdx.x;
    const int bid = blockIdx.x;
    const int qblk = bid >> 2;
    const int wq = bid & 3;
    const int m0 = bid * 32;
    const int wv = tid >> 6;
    const int l = tid & 63;
    const int h = l >> 5;
    const int ql = l & 31;
    u16* Wst0 = &WstBuf[0][0];
    u16* Wst1 = &WstBuf[1][0];

    stage_w_async(W1l, D, Wst0, tid);
    stage_w_async(W2l, HMID, Wst1, tid);

    if (tid < 32) {
        float L = 0.f;
#pragma unroll
        for (int ks = 0; ks < KSPLIT; ks++)
            L += ml[(size_t)(qblk * KSPLIT + ks) * 256 + 128 + wq * 32 + tid];
        Linv[tid] = 1.f / L;
    }
    __syncthreads();
    // ---- merge split-K partials (coalesced uint4) ----
    {
        const int dd = tid >> 1, qh = tid & 1;
        float acc[16];
#pragma unroll
        for (int i = 0; i < 16; i++) acc[i] = 0.f;
#pragma unroll
        for (int ks = 0; ks < KSPLIT; ks++) {
            const u16* p = Op + (((size_t)(qblk * KSPLIT + ks)) * 4 + wq) * (128 * 32) +
                           (size_t)dd * 32 + qh * 16;
            uint4 v0 = *(const uint4*)p;
            uint4 v1 = *(const uint4*)(p + 8);
            const u16* u0 = (const u16*)&v0;
            const u16* u1 = (const u16*)&v1;
#pragma unroll
            for (int j = 0; j < 8; j++) {
                acc[j] += bf2f(u0[j]);
                acc[8 + j] += bf2f(u1[j]);
            }
        }
#pragma unroll
        for (int i = 0; i < 16; i++) Ct[qh * 16 + i][dd] = acc[i] * Linv[qh * 16 + i];
    }
    __syncthreads();
    {
        const int d = tid & 127, rr = tid >> 7;
#pragma unroll
        for (int i = 0; i < 16; i++) {
            int row = rr * 16 + i;
            Ct[row][d] += H[(size_t)(m0 + row) * D + d];
        }
    }
    __syncthreads();
    build_as_fused(Ct, g2, b2l, As, tid);   // LN2 -> As
    __syncthreads();

    f32x16 a2;
#pragma unroll
    for (int r = 0; r < 16; r++) a2[r] = 0.f;
#pragma unroll
    for (int kc = 0; kc < 4; kc++) {
        if (kc >= 1) stage_w_async(W2l + (size_t)kc * 128, HMID, Wst1, tid);
        {
            f32x16 a = mm_32x128(As, Wst0, wv, ql, h);
            const int nl = wv * 32 + ql;
            const int ch2 = nl >> 3, sub = nl & 7;
            const float bv = b1l[kc * 128 + nl];
#pragma unroll
            for (int r = 0; r < 16; r++) {
                int row = (r & 3) + 8 * (r >> 2) + 4 * h;
                midS[((size_t)ch2 * 32 + (row ^ (ch2 & 7))) * 8 + sub] = f2bf(gelu_f(a[r] + bv));
            }
        }
        __syncthreads();
        if (kc < 3) stage_w_async(W1l + (size_t)(kc + 1) * 128 * D, D, Wst0, tid);
        else if (!LAST) stage_w_async(Wqkvn, D, Wst0, tid);
        {
            const int n = wv * 32 + ql, nsw = n & 7;
#pragma unroll
            for (int s = 0; s < 8; s++) {
                int ch = 2 * s + h;
                bf16x8 af = *(const bf16x8*)&midS[((size_t)ch * 32 + (ql ^ (ch & 7))) * 8];
                bf16x8 bf = *(const bf16x8*)&WstBuf[1][((size_t)n * 16 + (ch ^ nsw)) * 8];
                a2 = __builtin_amdgcn_mfma_f32_32x32x16_bf16(af, bf, a2, 0, 0, 0);
            }
        }
        __syncthreads();
    }
    {
        const int col = wv * 32 + ql;
        const float bv = b2bias[col];
#pragma unroll
        for (int r = 0; r < 16; r++) {
            int row = (r & 3) + 8 * (r >> 2) + 4 * h;
            float v = a2[r] + bv + Ct[row][col];
            Ct[row][col] = v;
            H[(size_t)(m0 + row) * D + col] = v;
        }
    }
    __syncthreads();
    if (LAST) {
        const int q = tid >> 3, e8 = tid & 7;
        float s = 0.f;
#pragma unroll
        for (int c = 0; c < 16; c++) s += Ct[q][e8 * 16 + c] * Wro[e8 * 16 + c];
        s += __shfl_xor(s, 1); s += __shfl_xor(s, 2); s += __shfl_xor(s, 4);
        if (e8 == 0) outp[m0 + q] = s + bro[0];
    } else {
        build_as_fused(Ct, g1n, b1n, As, tid);   // LN1'
        __syncthreads();
        stage_w_async(Wqkvn + (size_t)128 * D, D, Wst1, tid);
        {
            f32x16 a = mm_32x128(As, Wst0, wv, ql, h);
            const int n = wv * 32 + ql;
#pragma unroll
            for (int r = 0; r < 16; r++) {
                int row = (r & 3) + 8 * (r >> 2) + 4 * h;
                qb[(size_t)(m0 + row) * D + n] = f2bf(a[r]);
            }
        }
        __syncthreads();
        stage_w_async(Wqkvn + (size_t)256 * D, D, Wst0, tid);
        {
            f32x16 a = mm_32x128(As, Wst1, wv, ql, h);
            const int n = wv * 32 + ql;
#pragma unroll
            for (int r = 0; r < 16; r++) {
                int row = (r & 3) + 8 * (r >> 2) + 4 * h;
                kb[(size_t)(m0 + row) * D + n] = f2bf(a[r]);
            }
        }
        __syncthreads();
        {
            f32x16 a = mm_32x128(As, Wst0, wv, ql, h);
            const int n = wv * 32 + ql;
            u16* dst = vt + (size_t)(m0 >> 11) * D * T + (size_t)n * T + (m0 & (T - 1));
#pragma unroll
            for (int g = 0; g < 4; g++) {
                ushort4 o;
                o.x = f2bf(a[4 * g + 0]); o.y = f2bf(a[4 * g + 1]);
                o.z = f2bf(a[4 * g + 2]); o.w = f2bf(a[4 * g + 3]);
                *(ushort4*)(dst + 8 * g + 4 * h) = o;
            }
        }
    }
}

extern "C" void kernel_launch(void* const* d_in, const int* in_sizes, int n_in,
                              void* d_out, int out_size, void* d_ws, size_t ws_size,
                              hipStream_t stream) {
    const int* x = (const int*)d_in[0];
    const float* pos = (const float*)d_in[1];
    const float* Wq = (const float*)d_in[2];
    const float* Wk = (const float*)d_in[3];
    const float* Wv = (const float*)d_in[4];
    const float* ln1g = (const float*)d_in[5];
    const float* ln1b = (const float*)d_in[6];
    const float* W1 = (const float*)d_in[7];
    const float* b1 = (const float*)d_in[8];
    const float* W2 = (const float*)d_in[9];
    const float* b2 = (const float*)d_in[10];
    const float* ln2g = (const float*)d_in[11];
    const float* ln2b = (const float*)d_in[12];
    const float* Wro = (const float*)d_in[13];
    const float* bro = (const float*)d_in[14];
    float* out = (float*)d_out;

    const size_t NTOK = (size_t)BATCH * T;  // 8192
    const size_t HSZ = NTOK * D;            // 1,048,576
    float* ws = (float*)d_ws;
    float* H = ws;                                   // f32 [8192][128]
    u16* qb = (u16*)(ws + HSZ);                      // bf16 [8192][128]
    u16* kb = (u16*)(ws + HSZ + HSZ / 2);
    u16* vt = (u16*)(ws + 2 * HSZ);                  // bf16 [B][128][2048]
    u16* Op = (u16*)(ws + 2 * HSZ + HSZ / 2);        // bf16 partials 8.4 MB
    float* mlbuf = ws + 7 * HSZ;                     // f32 131072
    u16* Wqkv = (u16*)(ws + 7 * HSZ + 131072);       // bf16 [L][3*128][128]
    u16* W1b = Wqkv + (size_t)NLAYER * 3 * D * D;
    u16* W2b = W1b + (size_t)NLAYER * HMID * D;

    const float qscale = 1.4426950408889634f / 11.313708498984761f;  // log2(e)/sqrt(D)

    conv_all<<<dim3(8448), 256, 0, stream>>>(Wq, Wk, Wv, W1, W2, Wqkv, W1b, W2b, qscale);
    embed_qkv<<<dim3(256), 256, 0, stream>>>(x, pos, ln1g, ln1b, Wqkv, qb, kb, vt, H);

    for (int lay = 0; lay < NLAYER; lay++) {
        attn_mfma<<<dim3(64, KSPLIT), 256, 0, stream>>>(qb, kb, vt, Op, mlbuf);
        if (lay < NLAYER - 1) {
            layer_tail<0><<<dim3(256), 256, 0, stream>>>(
                Op, mlbuf, H,
                ln2g + (size_t)lay * D, ln2b + (size_t)lay * D,
                W1b + (size_t)lay * HMID * D, b1 + (size_t)lay * HMID,
                W2b + (size_t)lay * D * HMID, b2 + (size_t)lay * D,
                ln1g + (size_t)(lay + 1) * D, ln1b + (size_t)(lay + 1) * D,
                Wqkv + (size_t)(lay + 1) * 3 * D * D,
                qb, kb, vt, Wro, bro, nullptr);
        } else {
            layer_tail<1><<<dim3(256), 256, 0, stream>>>(
                Op, mlbuf, H,
                ln2g + (size_t)lay * D, ln2b + (size_t)lay * D,
                W1b + (size_t)lay * HMID * D, b1 + (size_t)lay * HMID,
                W2b + (size_t)lay * D * HMID, b2 + (size_t)lay * D,
                ln1g, ln1b, Wqkv,
                qb, kb, vt, Wro, bro, out);
        }
    }
}

// Round 15
// 543.270 us; speedup vs baseline: 1.1431x; 1.1431x over previous
//
#include <hip/hip_runtime.h>
#include <math.h>

#define D 128
#define T 2048
#define BATCH 4
#define HMID 512
#define NLAYER 12

#define KSPLIT 8
#define KPB (T / KSPLIT)   // 256 keys per attn block

#if defined(__has_builtin)
#if __has_builtin(__builtin_amdgcn_global_load_lds)
#define USE_GLL 1
#endif
#endif
#ifndef USE_GLL
#define USE_GLL 0
#endif

typedef unsigned short u16;
typedef __attribute__((ext_vector_type(8))) short bf16x8;
typedef __attribute__((ext_vector_type(16))) float f32x16;

__device__ inline u16 f2bf(float x) {
    unsigned u = __builtin_bit_cast(unsigned, x);
    return (u16)((u + 0x7FFFu + ((u >> 16) & 1u)) >> 16);
}
__device__ inline float bf2f(u16 v) {
    return __builtin_bit_cast(float, (unsigned)v << 16);
}
__device__ inline unsigned pkt(float a, float b) {
    return (__builtin_bit_cast(unsigned, a) >> 16) |
           (__builtin_bit_cast(unsigned, b) & 0xFFFF0000u);
}
// tanh-form gelu via exp2 (deviation <0.02 abs; mid is bf16 anyway)
__device__ inline float gelu_f(float v) {
    float y = 0.7978845608028654f * v * fmaf(0.044715f, v * v, 1.f);
    float e = exp2f(2.885390081777927f * y);
    return v * (1.f - 1.f / (e + 1.f));
}

// ================= helpers (32-row blocks, Ct pitch 132) =================
__device__ inline void build_as_fused(const float (*Ct)[132],
                                      const float* __restrict__ g,
                                      const float* __restrict__ bb,
                                      u16* As, int tid) {
    const int row = tid >> 3, e8 = tid & 7;
    float s = 0.f;
#pragma unroll
    for (int c = 0; c < 16; c++) s += Ct[row][e8 * 16 + c];
    s += __shfl_xor(s, 1); s += __shfl_xor(s, 2); s += __shfl_xor(s, 4);
    float mu = s * (1.f / D);
    float s2 = 0.f;
#pragma unroll
    for (int c = 0; c < 16; c++) {
        float d0 = Ct[row][e8 * 16 + c] - mu;
        s2 += d0 * d0;
    }
    s2 += __shfl_xor(s2, 1); s2 += __shfl_xor(s2, 2); s2 += __shfl_xor(s2, 4);
    float rs = rsqrtf(s2 * (1.f / D) + 1e-5f);
#pragma unroll
    for (int cc = 0; cc < 2; cc++) {
        int c = e8 * 2 + cc;
        u16 tmp[8];
#pragma unroll
        for (int j = 0; j < 8; j++) {
            int d = c * 8 + j;
            tmp[j] = f2bf((Ct[row][d] - mu) * rs * g[d] + bb[d]);
        }
        *(uint4*)&As[((size_t)c * 32 + (row ^ (c & 7))) * 8] = *(uint4*)tmp;
    }
}

// stage 128x128 bf16 tile; slot s holds W[row=s>>4][ch=(s&15)^(row&7)]
__device__ inline void stage_w_async(const u16* __restrict__ W, int ldw, u16* Wst, int tid) {
    const int w = tid >> 6, l = tid & 63;
#if USE_GLL
#pragma unroll
    for (int i = 0; i < 8; i++) {
        int s = i * 256 + w * 64 + l;
        int row = s >> 4, ch = (s & 15) ^ (row & 7);
        __builtin_amdgcn_global_load_lds(
            (const __attribute__((address_space(1))) void*)(W + (size_t)row * ldw + ch * 8),
            (__attribute__((address_space(3))) void*)&Wst[(i * 256 + w * 64) * 8], 16, 0, 0);
    }
#else
#pragma unroll
    for (int i = 0; i < 8; i++) {
        int s = tid + i * 256;
        int row = s >> 4, ch = (s & 15) ^ (row & 7);
        *(uint4*)&Wst[(size_t)s * 8] = *(const uint4*)(W + (size_t)row * ldw + ch * 8);
    }
#endif
}

// C[32 rows(reg)][128 n] = As(32xK128) @ Wst^T ; Wst in slot layout above
__device__ inline f32x16 mm_32x128(const u16* As, const u16* Wst, int wv, int ql, int h) {
    const int n = wv * 32 + ql, nsw = n & 7;
    f32x16 a;
#pragma unroll
    for (int r = 0; r < 16; r++) a[r] = 0.f;
#pragma unroll
    for (int s = 0; s < 8; s++) {
        int ch = 2 * s + h;
        bf16x8 af = *(const bf16x8*)&As[((size_t)ch * 32 + (ql ^ (ch & 7))) * 8];
        bf16x8 bf = *(const bf16x8*)&Wst[((size_t)n * 16 + (ch ^ nsw)) * 8];
        a = __builtin_amdgcn_mfma_f32_32x32x16_bf16(af, bf, a, 0, 0, 0);
    }
    return a;
}

// ================= weight conversion =================
__global__ __launch_bounds__(256) void conv_all(const float* __restrict__ Wq,
                                                const float* __restrict__ Wk,
                                                const float* __restrict__ Wv,
                                                const float* __restrict__ W1,
                                                const float* __restrict__ W2,
                                                u16* __restrict__ Wqkv,
                                                u16* __restrict__ W1b,
                                                u16* __restrict__ W2b, float qscale) {
    const int NQ = NLAYER * 3 * D * D;
    const int NW = NLAYER * HMID * D;
    int idx = blockIdx.x * 256 + threadIdx.x;
    if (idx < NQ) {
        int lN = idx / (3 * D * D);
        int rem = idx - lN * (3 * D * D);
        int s = rem >> 14;
        int off = rem & 16383;
        const float* src = (s == 0) ? Wq : ((s == 1) ? Wk : Wv);
        Wqkv[idx] = f2bf(src[lN * 16384 + off] * ((s == 0) ? qscale : 1.f));
    } else if (idx < NQ + NW) {
        W1b[idx - NQ] = f2bf(W1[idx - NQ]);
    } else if (idx < NQ + 2 * NW) {
        W2b[idx - NQ - NW] = f2bf(W2[idx - NQ - NW]);
    }
}

// ================= embed + LN1 + QKV (layer 0 prologue) =================
__global__ __launch_bounds__(256, 2) void embed_qkv(const int* __restrict__ x,
                                                    const float* __restrict__ pos,
                                                    const float* __restrict__ g1,
                                                    const float* __restrict__ b1g,
                                                    const u16* __restrict__ Wqkv0,
                                                    u16* __restrict__ qb, u16* __restrict__ kb,
                                                    u16* __restrict__ vt,
                                                    float* __restrict__ H) {
    __shared__ float Ct[32][132];
    __shared__ u16 As[16 * 32 * 8];
    __shared__ u16 Wst[16 * 128 * 8];
    const int tid = threadIdx.x;
    const int m0 = blockIdx.x * 32;
    const int wv = tid >> 6, l = tid & 63, h = l >> 5, ql = l & 31;
    {
        const int d = tid & 127, rr = tid >> 7;
#pragma unroll
        for (int i = 0; i < 16; i++) {
            int row = rr * 16 + i;
            int tok = m0 + row;
            int t = tok & (T - 1);
            float e = 0.f;
            if (d < 64) {
                float diff = (float)d - (float)x[tok];
                e = -0.5f * diff * diff;
            }
            float v = e + pos[(size_t)t * D + d];
            Ct[row][d] = v;
            H[(size_t)tok * D + d] = v;
        }
    }
    __syncthreads();
    build_as_fused(Ct, g1, b1g, As, tid);
#pragma unroll
    for (int sl = 0; sl < 3; sl++) {
        __syncthreads();
        stage_w_async(Wqkv0 + (size_t)sl * 128 * D, D, Wst, tid);
        __syncthreads();
        f32x16 a = mm_32x128(As, Wst, wv, ql, h);
        const int n = wv * 32 + ql;
        if (sl == 2) {
            u16* dst = vt + (size_t)(m0 >> 11) * D * T + (size_t)n * T + (m0 & (T - 1));
#pragma unroll
            for (int g = 0; g < 4; g++) {
                ushort4 o;
                o.x = f2bf(a[4 * g + 0]); o.y = f2bf(a[4 * g + 1]);
                o.z = f2bf(a[4 * g + 2]); o.w = f2bf(a[4 * g + 3]);
                *(ushort4*)(dst + 8 * g + 4 * h) = o;
            }
        } else {
            u16* dst = (sl == 0) ? qb : kb;
#pragma unroll
            for (int r = 0; r < 16; r++) {
                int row = (r & 3) + 8 * (r >> 2) + 4 * h;
                dst[(size_t)(m0 + row) * D + n] = f2bf(a[r]);
            }
        }
    }
}

// ===== MFMA flash attention: KSPLIT=8, 64-key tiles DOUBLE-BUFFERED, 2 blocks/CU =====
// LDS 2 x (16K + 16V) = 64 KB (same as R13's single buffer -> occupancy kept),
// prefetch next tile before computing current (R13-tail pattern).
__device__ inline void stage_kv64(const u16* __restrict__ kgb, const u16* __restrict__ vtb,
                                  int kbase, u16* Ks, u16* Vt, int tid) {
    const int w = tid >> 6, l = tid & 63;
#if USE_GLL
#pragma unroll
    for (int i = 0; i < 4; i++) {
        int s = i * 256 + w * 64 + l;
        int row = s >> 4, ch = (s & 15) ^ (row & 7);
        __builtin_amdgcn_global_load_lds(
            (const __attribute__((address_space(1))) void*)(kgb + (size_t)(kbase + row) * D + ch * 8),
            (__attribute__((address_space(3))) void*)&Ks[(i * 256 + w * 64) * 8], 16, 0, 0);
    }
#pragma unroll
    for (int i = 0; i < 4; i++) {
        int s = i * 256 + w * 64 + l;
        int dd = s >> 3, kc = (s & 7) ^ (dd & 7);
        __builtin_amdgcn_global_load_lds(
            (const __attribute__((address_space(1))) void*)(vtb + (size_t)dd * T + kbase + kc * 8),
            (__attribute__((address_space(3))) void*)&Vt[(i * 256 + w * 64) * 8], 16, 0, 0);
    }
#else
#pragma unroll
    for (int i = 0; i < 4; i++) {
        int s = tid + i * 256;
        int row = s >> 4, ch = (s & 15) ^ (row & 7);
        *(uint4*)&Ks[(size_t)s * 8] = *(const uint4*)(kgb + (size_t)(kbase + row) * D + ch * 8);
        int dd = s >> 3, kc = (s & 7) ^ (dd & 7);
        *(uint4*)&Vt[(size_t)s * 8] = *(const uint4*)(vtb + (size_t)dd * T + kbase + kc * 8);
    }
#endif
}

__global__ __launch_bounds__(256, 2) void attn_mfma(const u16* __restrict__ qg,
                                                    const u16* __restrict__ kg,
                                                    const u16* __restrict__ vtg,
                                                    u16* __restrict__ Op,
                                                    float* __restrict__ ml) {
    __shared__ u16 KsBuf[2][64 * 128];   // 2 x 16 KB
    __shared__ u16 VtBuf[2][128 * 64];   // 2 x 16 KB
    const int tid = threadIdx.x;
    const int w = tid >> 6;
    const int l = tid & 63;
    const int h = l >> 5;
    const int ql = l & 31;
    const int qblk = blockIdx.x;
    const int ks = blockIdx.y;
    const int b = qblk >> 4;

    const size_t qrow = (size_t)qblk * 128 + w * 32 + ql;
    bf16x8 qf[8];
#pragma unroll
    for (int c = 0; c < 8; c++)
        qf[c] = *(const bf16x8*)(qg + qrow * D + c * 16 + h * 8);

    f32x16 ot[4];
#pragma unroll
    for (int t = 0; t < 4; t++)
#pragma unroll
        for (int r = 0; r < 16; r++) ot[t][r] = 0.f;
    float l_run = 0.f;

    const u16* kgb = kg + (size_t)b * T * D;
    const u16* vtb = vtg + (size_t)b * D * T;

    stage_kv64(kgb, vtb, ks * KPB, KsBuf[0], VtBuf[0], tid);
    __syncthreads();

    for (int kt = 0; kt < KPB / 64; kt++) {   // 4 tiles of 64 keys
        const int p = kt & 1;
        if (kt + 1 < KPB / 64)
            stage_kv64(kgb, vtb, ks * KPB + (kt + 1) * 64, KsBuf[1 - p], VtBuf[1 - p], tid);
        const u16* Ks = KsBuf[p];
        const u16* Vt = VtBuf[p];
        uint2 pk[2][4];
        float rs = 0.f;
#pragma unroll
        for (int s4 = 0; s4 < 2; s4++) {
            const int krow = s4 * 32 + ql;
            const int ksw = krow & 7;
            f32x16 st;
#pragma unroll
            for (int r = 0; r < 16; r++) st[r] = 0.f;
#pragma unroll
            for (int c = 0; c < 8; c++) {
                bf16x8 kf = *(const bf16x8*)&Ks[((size_t)krow * 16 + ((2 * c + h) ^ ksw)) * 8];
                st = __builtin_amdgcn_mfma_f32_32x32x16_bf16(kf, qf[c], st, 0, 0, 0);
            }
#pragma unroll
            for (int r = 0; r < 16; r++) {
                float p2 = exp2f(st[r]);
                st[r] = p2;
                rs += p2;
            }
#pragma unroll
            for (int g = 0; g < 4; g++) {
                pk[s4][g].x = pkt(st[4 * g + 0], st[4 * g + 1]);
                pk[s4][g].y = pkt(st[4 * g + 2], st[4 * g + 3]);
            }
        }
        rs += __shfl_xor(rs, 32);
        l_run += rs;
#pragma unroll
        for (int c = 0; c < 4; c++) {   // 4 key-chunks of 16 within the 64-key tile
            const int s4 = c >> 1, cc = c & 1;
            uint2 own = h ? pk[s4][2 * cc + 1] : pk[s4][2 * cc];
            uint2 snd = h ? pk[s4][2 * cc] : pk[s4][2 * cc + 1];
            uint2 rcv;
            rcv.x = (unsigned)__shfl_xor((int)snd.x, 32);
            rcv.y = (unsigned)__shfl_xor((int)snd.y, 32);
            uint4 fr;
            fr.x = h ? rcv.x : own.x;
            fr.y = h ? rcv.y : own.y;
            fr.z = h ? own.x : rcv.x;
            fr.w = h ? own.y : rcv.y;
            bf16x8 pf = __builtin_bit_cast(bf16x8, fr);
            const int kch = 2 * c + h;   // chunk of 8 keys, 0..7
#pragma unroll
            for (int t = 0; t < 4; t++) {
                const int drow = t * 32 + ql;
                bf16x8 vf = *(const bf16x8*)&Vt[((size_t)drow * 8 + (kch ^ (drow & 7))) * 8];
                ot[t] = __builtin_amdgcn_mfma_f32_32x32x16_bf16(vf, pf, ot[t], 0, 0, 0);
            }
        }
        __syncthreads();   // drains prefetch kt+1 — issued before compute, mostly free
    }
    size_t base = (((size_t)(qblk * KSPLIT + ks)) * 4 + w) * (128 * 32);
#pragma unroll
    for (int t = 0; t < 4; t++)
#pragma unroll
        for (int r = 0; r < 16; r++) {
            int dd = (r & 3) + 8 * (r >> 2) + 4 * h + 32 * t;
            Op[base + (size_t)dd * 32 + ql] = f2bf(ot[t][r]);
        }
    if (h == 0) {
        int qi = w * 32 + ql;
        ml[(size_t)(qblk * KSPLIT + ks) * 256 + 128 + qi] = l_run;
    }
}

// ====== layer tail: merge + resid + LN2 + MLP + resid + LN1' + QKV' ======
// Double-buffered pipelined weight staging (R13), LDS ~97 KB, 1 block/CU.
template <int LAST>
__global__ __launch_bounds__(256, 1) void layer_tail(
    const u16* __restrict__ Op, const float* __restrict__ ml,
    float* __restrict__ H,
    const float* __restrict__ g2, const float* __restrict__ b2l,
    const u16* __restrict__ W1l, const float* __restrict__ b1l,
    const u16* __restrict__ W2l, const float* __restrict__ b2bias,
    const float* __restrict__ g1n, const float* __restrict__ b1n,
    const u16* __restrict__ Wqkvn,
    u16* __restrict__ qb, u16* __restrict__ kb, u16* __restrict__ vt,
    const float* __restrict__ Wro, const float* __restrict__ bro,
    float* __restrict__ outp) {
    __shared__ float Ct[32][132];
    __shared__ float Linv[32];
    __shared__ u16 As[16 * 32 * 8];
    __shared__ u16 midS[16 * 32 * 8];
    __shared__ u16 WstBuf[2][16 * 128 * 8];

    const int tid = threadIdx.x;
    const int bid = blockIdx.x;
    const int qblk = bid >> 2;
    const int wq = bid & 3;
    const int m0 = bid * 32;
    const int wv = tid >> 6;
    const int l = tid & 63;
    const int h = l >> 5;
    const int ql = l & 31;
    u16* Wst0 = &WstBuf[0][0];
    u16* Wst1 = &WstBuf[1][0];

    stage_w_async(W1l, D, Wst0, tid);
    stage_w_async(W2l, HMID, Wst1, tid);

    if (tid < 32) {
        float L = 0.f;
#pragma unroll
        for (int ks = 0; ks < KSPLIT; ks++)
            L += ml[(size_t)(qblk * KSPLIT + ks) * 256 + 128 + wq * 32 + tid];
        Linv[tid] = 1.f / L;
    }
    __syncthreads();
    // ---- merge split-K partials (coalesced uint4) ----
    {
        const int dd = tid >> 1, qh = tid & 1;
        float acc[16];
#pragma unroll
        for (int i = 0; i < 16; i++) acc[i] = 0.f;
#pragma unroll
        for (int ks = 0; ks < KSPLIT; ks++) {
            const u16* p = Op + (((size_t)(qblk * KSPLIT + ks)) * 4 + wq) * (128 * 32) +
                           (size_t)dd * 32 + qh * 16;
            uint4 v0 = *(const uint4*)p;
            uint4 v1 = *(const uint4*)(p + 8);
            const u16* u0 = (const u16*)&v0;
            const u16* u1 = (const u16*)&v1;
#pragma unroll
            for (int j = 0; j < 8; j++) {
                acc[j] += bf2f(u0[j]);
                acc[8 + j] += bf2f(u1[j]);
            }
        }
#pragma unroll
        for (int i = 0; i < 16; i++) Ct[qh * 16 + i][dd] = acc[i] * Linv[qh * 16 + i];
    }
    __syncthreads();
    {
        const int d = tid & 127, rr = tid >> 7;
#pragma unroll
        for (int i = 0; i < 16; i++) {
            int row = rr * 16 + i;
            Ct[row][d] += H[(size_t)(m0 + row) * D + d];
        }
    }
    __syncthreads();
    build_as_fused(Ct, g2, b2l, As, tid);   // LN2 -> As
    __syncthreads();

    f32x16 a2;
#pragma unroll
    for (int r = 0; r < 16; r++) a2[r] = 0.f;
#pragma unroll
    for (int kc = 0; kc < 4; kc++) {
        if (kc >= 1) stage_w_async(W2l + (size_t)kc * 128, HMID, Wst1, tid);
        {
            f32x16 a = mm_32x128(As, Wst0, wv, ql, h);
            const int nl = wv * 32 + ql;
            const int ch2 = nl >> 3, sub = nl & 7;
            const float bv = b1l[kc * 128 + nl];
#pragma unroll
            for (int r = 0; r < 16; r++) {
                int row = (r & 3) + 8 * (r >> 2) + 4 * h;
                midS[((size_t)ch2 * 32 + (row ^ (ch2 & 7))) * 8 + sub] = f2bf(gelu_f(a[r] + bv));
            }
        }
        __syncthreads();
        if (kc < 3) stage_w_async(W1l + (size_t)(kc + 1) * 128 * D, D, Wst0, tid);
        else if (!LAST) stage_w_async(Wqkvn, D, Wst0, tid);
        {
            const int n = wv * 32 + ql, nsw = n & 7;
#pragma unroll
            for (int s = 0; s < 8; s++) {
                int ch = 2 * s + h;
                bf16x8 af = *(const bf16x8*)&midS[((size_t)ch * 32 + (ql ^ (ch & 7))) * 8];
                bf16x8 bf = *(const bf16x8*)&WstBuf[1][((size_t)n * 16 + (ch ^ nsw)) * 8];
                a2 = __builtin_amdgcn_mfma_f32_32x32x16_bf16(af, bf, a2, 0, 0, 0);
            }
        }
        __syncthreads();
    }
    {
        const int col = wv * 32 + ql;
        const float bv = b2bias[col];
#pragma unroll
        for (int r = 0; r < 16; r++) {
            int row = (r & 3) + 8 * (r >> 2) + 4 * h;
            float v = a2[r] + bv + Ct[row][col];
            Ct[row][col] = v;
            H[(size_t)(m0 + row) * D + col] = v;
        }
    }
    __syncthreads();
    if (LAST) {
        const int q = tid >> 3, e8 = tid & 7;
        float s = 0.f;
#pragma unroll
        for (int c = 0; c < 16; c++) s += Ct[q][e8 * 16 + c] * Wro[e8 * 16 + c];
        s += __shfl_xor(s, 1); s += __shfl_xor(s, 2); s += __shfl_xor(s, 4);
        if (e8 == 0) outp[m0 + q] = s + bro[0];
    } else {
        build_as_fused(Ct, g1n, b1n, As, tid);   // LN1'
        __syncthreads();
        stage_w_async(Wqkvn + (size_t)128 * D, D, Wst1, tid);
        {
            f32x16 a = mm_32x128(As, Wst0, wv, ql, h);
            const int n = wv * 32 + ql;
#pragma unroll
            for (int r = 0; r < 16; r++) {
                int row = (r & 3) + 8 * (r >> 2) + 4 * h;
                qb[(size_t)(m0 + row) * D + n] = f2bf(a[r]);
            }
        }
        __syncthreads();
        stage_w_async(Wqkvn + (size_t)256 * D, D, Wst0, tid);
        {
            f32x16 a = mm_32x128(As, Wst1, wv, ql, h);
            const int n = wv * 32 + ql;
#pragma unroll
            for (int r = 0; r < 16; r++) {
                int row = (r & 3) + 8 * (r >> 2) + 4 * h;
                kb[(size_t)(m0 + row) * D + n] = f2bf(a[r]);
            }
        }
        __syncthreads();
        {
            f32x16 a = mm_32x128(As, Wst0, wv, ql, h);
            const int n = wv * 32 + ql;
            u16* dst = vt + (size_t)(m0 >> 11) * D * T + (size_t)n * T + (m0 & (T - 1));
#pragma unroll
            for (int g = 0; g < 4; g++) {
                ushort4 o;
                o.x = f2bf(a[4 * g + 0]); o.y = f2bf(a[4 * g + 1]);
                o.z = f2bf(a[4 * g + 2]); o.w = f2bf(a[4 * g + 3]);
                *(ushort4*)(dst + 8 * g + 4 * h) = o;
            }
        }
    }
}

extern "C" void kernel_launch(void* const* d_in, const int* in_sizes, int n_in,
                              void* d_out, int out_size, void* d_ws, size_t ws_size,
                              hipStream_t stream) {
    const int* x = (const int*)d_in[0];
    const float* pos = (const float*)d_in[1];
    const float* Wq = (const float*)d_in[2];
    const float* Wk = (const float*)d_in[3];
    const float* Wv = (const float*)d_in[4];
    const float* ln1g = (const float*)d_in[5];
    const float* ln1b = (const float*)d_in[6];
    const float* W1 = (const float*)d_in[7];
    const float* b1 = (const float*)d_in[8];
    const float* W2 = (const float*)d_in[9];
    const float* b2 = (const float*)d_in[10];
    const float* ln2g = (const float*)d_in[11];
    const float* ln2b = (const float*)d_in[12];
    const float* Wro = (const float*)d_in[13];
    const float* bro = (const float*)d_in[14];
    float* out = (float*)d_out;

    const size_t NTOK = (size_t)BATCH * T;  // 8192
    const size_t HSZ = NTOK * D;            // 1,048,576
    float* ws = (float*)d_ws;
    float* H = ws;                                   // f32 [8192][128]
    u16* qb = (u16*)(ws + HSZ);                      // bf16 [8192][128]
    u16* kb = (u16*)(ws + HSZ + HSZ / 2);
    u16* vt = (u16*)(ws + 2 * HSZ);                  // bf16 [B][128][2048]
    u16* Op = (u16*)(ws + 2 * HSZ + HSZ / 2);        // bf16 partials 16.8 MB
    float* mlbuf = ws + 7 * HSZ;                     // f32 131072
    u16* Wqkv = (u16*)(ws + 7 * HSZ + 131072);       // bf16 [L][3*128][128]
    u16* W1b = Wqkv + (size_t)NLAYER * 3 * D * D;
    u16* W2b = W1b + (size_t)NLAYER * HMID * D;

    const float qscale = 1.4426950408889634f / 11.313708498984761f;  // log2(e)/sqrt(D)

    conv_all<<<dim3(8448), 256, 0, stream>>>(Wq, Wk, Wv, W1, W2, Wqkv, W1b, W2b, qscale);
    embed_qkv<<<dim3(256), 256, 0, stream>>>(x, pos, ln1g, ln1b, Wqkv, qb, kb, vt, H);

    for (int lay = 0; lay < NLAYER; lay++) {
        attn_mfma<<<dim3(64, KSPLIT), 256, 0, stream>>>(qb, kb, vt, Op, mlbuf);
        if (lay < NLAYER - 1) {
            layer_tail<0><<<dim3(256), 256, 0, stream>>>(
                Op, mlbuf, H,
                ln2g + (size_t)lay * D, ln2b + (size_t)lay * D,
                W1b + (size_t)lay * HMID * D, b1 + (size_t)lay * HMID,
                W2b + (size_t)lay * D * HMID, b2 + (size_t)lay * D,
                ln1g + (size_t)(lay + 1) * D, ln1b + (size_t)(lay + 1) * D,
                Wqkv + (size_t)(lay + 1) * 3 * D * D,
                qb, kb, vt, Wro, bro, nullptr);
        } else {
            layer_tail<1><<<dim3(256), 256, 0, stream>>>(
                Op, mlbuf, H,
                ln2g + (size_t)lay * D, ln2b + (size_t)lay * D,
                W1b + (size_t)lay * HMID * D, b1 + (size_t)lay * HMID,
                W2b + (size_t)lay * D * HMID, b2 + (size_t)lay * D,
                ln1g, ln1b, Wqkv,
                qb, kb, vt, Wro, bro, out);
        }
    }
}